// Round 4
// baseline (273.871 us; speedup 1.0000x reference)
//
#include <hip/hip_runtime.h>
#include <hip/hip_bf16.h>

// HMM count-accumulation, atomic-free emit path, single-read phase1.
// out = [trans_count 65*65=4225 | emit_count 500000*64=32M] floats.
//
// R2 finding: scattered device-scope float atomics plateau (~165us) independent
// of occupancy. R3 design (bucket-by-partition) works; R4 tightens it:
//  - phase1 reads the token stream ONCE (keys cached in a 32KB LDS tile buffer)
//  - phase2 covers a whole partition in one 62.4KB LDS chunk of packed u16
//    counts (P=1025 x CPP=31232), one zero + one scan + one write sweep
//  - trans finalize fused into phase2's grid (blocks >= P)

constexpr int N_WORDS  = 500000;
constexpr int N_LABELS = 64;
constexpr int SEQ_LEN  = 512;
constexpr int BINS     = (N_LABELS + 1) * (N_LABELS + 1);   // 4225
constexpr int N_CELLS  = N_WORDS * N_LABELS;                // 32,000,000
constexpr int P        = 1025;    // emit partitions
constexpr int CPP      = 31232;   // cells/partition (u16 counts fit 62.4KB LDS)
constexpr int CAP      = 8192;    // key slots per partition (mean ~3075, +93 sigma)
constexpr int B1 = 1024, G1 = 512;
constexpr int TILE_TOK = 8192;    // tokens per phase1 tile (= B1*4*2)
constexpr int B2 = 1024;
constexpr int FIN_BLOCKS = 5;     // fused trans-finalize blocks (5*1024 >= 4225)

// ---------------- phase 1: count + bucket keys + trans hist ----------------

__global__ __launch_bounds__(B1)
void phase1(const int* __restrict__ words, const int* __restrict__ labels,
            unsigned* __restrict__ cursors,        // [P] reservation cursors (zeroed)
            unsigned short* __restrict__ keys,     // [P][CAP] local cell ids
            unsigned* __restrict__ part_t,         // [G1][BINS] trans partials
            int n) {
    __shared__ unsigned trans[BINS];       // 16.9 KB
    __shared__ unsigned keybuf[TILE_TOK];  // 32 KB packed (p<<16)|loc, ~0u = pad
    __shared__ unsigned cnt[P];            // 4.1 KB
    __shared__ unsigned base[P];
    __shared__ unsigned pos[P];
    for (int k = threadIdx.x; k < BINS; k += B1) trans[k] = 0u;
    __syncthreads();

    const int nquads = n >> 2;
    const int qpt    = TILE_TOK >> 2;                 // 2048 quads/tile
    const int ntiles = (nquads + qpt - 1) / qpt;

    for (int tile = blockIdx.x; tile < ntiles; tile += gridDim.x) {
        const int q0     = tile * qpt;
        const int tquads = min(qpt, nquads - q0);

        for (int k = threadIdx.x; k < P; k += B1) { cnt[k] = 0u; pos[k] = 0u; }
        __syncthreads();

        // pass A: load once, compute keys -> LDS, partition counts, trans hist
        for (int lq = threadIdx.x; lq < tquads; lq += B1) {
            const int q = q0 + lq;
            const int i = q << 2;
            const int4 w4 = reinterpret_cast<const int4*>(words)[q];
            const int4 l4 = reinterpret_cast<const int4*>(labels)[q];
            const int j0 = i & (SEQ_LEN - 1);
            int pre = (j0 == 0) ? N_LABELS : labels[i - 1];
            int wv[4] = {w4.x, w4.y, w4.z, w4.w};
            int lv[4] = {l4.x, l4.y, l4.z, l4.w};
            #pragma unroll
            for (int k = 0; k < 4; ++k) {
                const int lab = lv[k];
                unsigned pack = 0xFFFFFFFFu;
                if (wv[k] != 0) {
                    atomicAdd(&trans[lab * (N_LABELS + 1) + pre], 1u);
                    const int w = (wv[k] >= N_WORDS) ? 1 : wv[k];
                    const unsigned key = (unsigned)w * N_LABELS + (unsigned)lab;
                    const unsigned p   = key / CPP;
                    pack = (p << 16) | (key - p * CPP);
                    atomicAdd(&cnt[p], 1u);
                }
                keybuf[(lq << 2) + k] = pack;
                pre = lab;
            }
        }
        __syncthreads();

        // reservation: ONE device atomic per (block, partition)
        for (int p = threadIdx.x; p < P; p += B1) {
            const unsigned c = cnt[p];
            base[p] = c ? atomicAdd(&cursors[p], c) : 0u;
        }
        __syncthreads();

        // pass B: place keys from LDS (no global re-read)
        const int ttok = tquads << 2;
        for (int t = threadIdx.x; t < ttok; t += B1) {
            const unsigned pack = keybuf[t];
            if (pack != 0xFFFFFFFFu) {
                const unsigned p   = pack >> 16;
                const unsigned loc = pack & 0xFFFFu;
                const unsigned slot = base[p] + atomicAdd(&pos[p], 1u);
                if (slot < CAP)
                    keys[(size_t)p * CAP + slot] = (unsigned short)loc;
            }
        }
        __syncthreads();
    }

    // flush trans partial with plain coalesced stores
    unsigned* my = part_t + (size_t)blockIdx.x * BINS;
    for (int k = threadIdx.x; k < BINS; k += B1) my[k] = trans[k];
}

// ---------------- phase 2: build emit slices + fused trans finalize ----------------

__global__ __launch_bounds__(B2)
void phase2(const unsigned* __restrict__ cursors,
            const unsigned short* __restrict__ keys,
            const unsigned* __restrict__ part_t,
            float* __restrict__ out) {
    extern __shared__ unsigned h[];          // CPP/2 u32 = 62,464 B packed u16 counts
    const unsigned bid = blockIdx.x;

    if (bid >= (unsigned)P) {                // fused trans finalize
        const int k = (bid - P) * B2 + threadIdx.x;
        if (k < BINS) {
            unsigned s = 0;
            #pragma unroll 8
            for (int pb = 0; pb < G1; ++pb) s += part_t[(size_t)pb * BINS + k];
            out[k] = (float)s;
        }
        return;
    }

    float* __restrict__ emit = out + BINS;
    const unsigned base_cell = bid * (unsigned)CPP;
    const unsigned cells = min((unsigned)CPP, (unsigned)N_CELLS - base_cell);
    const unsigned n32 = (cells + 1u) >> 1;
    unsigned nk = cursors[bid]; if (nk > CAP) nk = CAP;
    const unsigned short* kp = keys + (size_t)bid * CAP;

    for (unsigned j = threadIdx.x; j < n32; j += B2) h[j] = 0u;
    __syncthreads();
    for (unsigned i = threadIdx.x; i < nk; i += B2) {
        const unsigned c = kp[i];
        atomicAdd(&h[c >> 1], (c & 1u) ? 65536u : 1u);
    }
    __syncthreads();
    for (unsigned j = threadIdx.x; j < cells; j += B2) {
        const unsigned v = h[j >> 1];
        const unsigned c = (j & 1u) ? (v >> 16) : (v & 0xFFFFu);
        emit[base_cell + j] = (float)c;
    }
}

// ---------------- fallback path (used only if ws too small) ----------------

__global__ __launch_bounds__(256)
void zero_kernel(uint4* __restrict__ out, int out_quads, int out_size) {
    const uint4 z = {0u, 0u, 0u, 0u};
    const int stride = gridDim.x * blockDim.x;
    for (int q = blockIdx.x * blockDim.x + threadIdx.x; q < out_quads; q += stride)
        out[q] = z;
    if (blockIdx.x == 0 && threadIdx.x < (out_size & 3))
        ((unsigned*)out)[(out_quads << 2) + threadIdx.x] = 0u;
}

__global__ __launch_bounds__(1024)
void count_fallback(const int* __restrict__ words, const int* __restrict__ labels,
                    float* __restrict__ out, int nquads) {
    __shared__ unsigned hist[BINS];
    for (int k = threadIdx.x; k < BINS; k += 1024) hist[k] = 0u;
    __syncthreads();
    float* __restrict__ emit = out + BINS;
    const int stride = gridDim.x * blockDim.x;
    for (int q = blockIdx.x * blockDim.x + threadIdx.x; q < nquads; q += stride) {
        const int i = q << 2;
        const int4 w4 = reinterpret_cast<const int4*>(words)[q];
        const int4 l4 = reinterpret_cast<const int4*>(labels)[q];
        const int j0 = i & (SEQ_LEN - 1);
        int pre = (j0 == 0) ? N_LABELS : labels[i - 1];
        int wv[4] = {w4.x, w4.y, w4.z, w4.w};
        int lv[4] = {l4.x, l4.y, l4.z, l4.w};
        #pragma unroll
        for (int k = 0; k < 4; ++k) {
            const int w = wv[k], lab = lv[k];
            if (w != 0) {
                atomicAdd(&hist[lab * (N_LABELS + 1) + pre], 1u);
                const int we = (w >= N_WORDS) ? 1 : w;
                atomicAdd(&emit[(size_t)we * N_LABELS + lab], 1.0f);
            }
            pre = lab;
        }
    }
    __syncthreads();
    for (int k = threadIdx.x; k < 1024 * 8 && k < BINS; k += 1024) {}
    for (int k = threadIdx.x; k < BINS; k += 1024) {
        const unsigned c = hist[k];
        if (c) atomicAdd(&out[k], (float)c);
    }
}

// ---------------- launch ----------------

extern "C" void kernel_launch(void* const* d_in, const int* in_sizes, int n_in,
                              void* d_out, int out_size, void* d_ws, size_t ws_size,
                              hipStream_t stream) {
    const int* words  = (const int*)d_in[0];
    const int* labels = (const int*)d_in[1];
    float* out = (float*)d_out;

    const int n = in_sizes[0];

    // ws layout: [0,8KB) cursors | keys (P*CAP*2 = 16.8MB) | part_t (8.65MB)
    const size_t cur_off   = 0;
    const size_t key_off   = 8192;
    const size_t key_bytes = (size_t)P * CAP * sizeof(unsigned short);
    const size_t part_off  = key_off + key_bytes;
    const size_t part_bytes = (size_t)G1 * BINS * sizeof(unsigned);
    const size_t need = part_off + part_bytes;

    if (ws_size >= need) {
        unsigned* cursors    = (unsigned*)((char*)d_ws + cur_off);
        unsigned short* keys = (unsigned short*)((char*)d_ws + key_off);
        unsigned* part_t     = (unsigned*)((char*)d_ws + part_off);

        hipMemsetAsync(cursors, 0, P * sizeof(unsigned), stream);
        phase1<<<G1, B1, 0, stream>>>(words, labels, cursors, keys, part_t, n);
        phase2<<<P + FIN_BLOCKS, B2, (CPP / 2) * sizeof(unsigned), stream>>>(
            cursors, keys, part_t, out);
    } else {
        const int out_quads = out_size >> 2;
        zero_kernel<<<2048, 256, 0, stream>>>((uint4*)d_out, out_quads, out_size);
        count_fallback<<<512, 1024, 0, stream>>>(words, labels, out, n >> 2);
    }
}